// Round 8
// baseline (366.116 us; speedup 1.0000x reference)
//
#include <hip/hip_runtime.h>

typedef __bf16 bf16x8 __attribute__((ext_vector_type(8)));
typedef float f32x4 __attribute__((ext_vector_type(4)));
typedef short short8 __attribute__((ext_vector_type(8)));

#define MFMA16(a, b, c) __builtin_amdgcn_mfma_f32_16x16x32_bf16(a, b, c, 0, 0, 0)

__device__ inline unsigned short bf16_rne(float x) {
  unsigned u = __builtin_bit_cast(unsigned, x);
  return (unsigned short)((u + 0x7FFFu + ((u >> 16) & 1u)) >> 16);
}
__device__ inline float bf16_tof(unsigned short s) {
  unsigned u = ((unsigned)s) << 16;
  return __builtin_bit_cast(float, u);
}
__device__ inline void split2(float x, unsigned short* hi, unsigned short* lo) {
  unsigned short h = bf16_rne(x);
  *hi = h;
  *lo = bf16_rne(x - bf16_tof(h));
}

// ---------------- fp32 -> (hi, lo) bf16 split ----------------

__global__ __launch_bounds__(256) void conv_split_kernel(
    const float* __restrict__ x, unsigned short* __restrict__ xhi,
    unsigned short* __restrict__ xlo, int total4) {
  int i = blockIdx.x * 256 + threadIdx.x;
  if (i < total4) {
    float4 v = ((const float4*)x)[i];
    ushort4 h, l;
    split2(v.x, &h.x, &l.x);
    split2(v.y, &h.y, &l.y);
    split2(v.z, &h.z, &l.z);
    split2(v.w, &h.w, &l.w);
    ((ushort4*)xhi)[i] = h;
    ((ushort4*)xlo)[i] = l;
  }
}

// ---------------- weight frag prep ----------------

__global__ __launch_bounds__(256) void wprep_kernel(
    const float* __restrict__ W, const float* __restrict__ w_ih,
    const float* __restrict__ w_hh, unsigned short* __restrict__ frags) {
  int idx = blockIdx.x * 256 + threadIdx.x;
  if (idx >= 3 * 12 * 2 * 64) return;
  int lane = idx & 63;
  int ks = (idx >> 6) & 1;
  int tci = (idx >> 7) % 12;
  int set = idx / (12 * 2 * 64);
  int c = tci * 16 + (lane & 15);
  unsigned short* hi = frags + (size_t)set * 2 * 12288;
  unsigned short* lo = hi + 12288;
  size_t dbase = ((size_t)(tci * 2 + ks) * 64 + lane) * 8;
#pragma unroll
  for (int j = 0; j < 8; ++j) {
    int k = ks * 32 + ((lane >> 4) << 3) + j;
    float v;
    if (set == 0) v = W[((c >> 6) << 12) + (k << 6) + (c & 63)];
    else if (set == 1) v = w_ih[(c << 6) + k];
    else v = w_hh[(c << 6) + k];
    unsigned short h, l;
    split2(v, &h, &l);
    hi[dbase + j] = h;
    lo[dbase + j] = l;
  }
}

// ---------------- CSR build ----------------

__global__ __launch_bounds__(256) void count_kernel(
    const int* __restrict__ dst, unsigned* __restrict__ counts, int E) {
  int base = (blockIdx.x * 256 + threadIdx.x) * 4;
  if (base + 4 <= E) {
    int4 d = *(const int4*)(dst + base);
    atomicAdd(&counts[d.x], 1u);
    atomicAdd(&counts[d.y], 1u);
    atomicAdd(&counts[d.z], 1u);
    atomicAdd(&counts[d.w], 1u);
  } else {
    for (int k = base; k < E; ++k) atomicAdd(&counts[dst[k]], 1u);
  }
}

__global__ __launch_bounds__(1024) void scan_k1(
    const unsigned* __restrict__ counts, unsigned* __restrict__ offs,
    unsigned* __restrict__ bsums, int N) {
  __shared__ unsigned sm[1024];
  int tid = threadIdx.x;
  int i = blockIdx.x * 1024 + tid;
  unsigned v = (i < N) ? counts[i] : 0u;
  sm[tid] = v;
  __syncthreads();
  for (int ofs = 1; ofs < 1024; ofs <<= 1) {
    unsigned add = (tid >= ofs) ? sm[tid - ofs] : 0u;
    __syncthreads();
    sm[tid] += add;
    __syncthreads();
  }
  if (i < N) offs[i] = sm[tid] - v;
  if (tid == 0) bsums[blockIdx.x] = sm[1023];
}

__global__ __launch_bounds__(128) void scan_k2(
    unsigned* __restrict__ bsums, unsigned* __restrict__ offs, int M, int N) {
  __shared__ unsigned sm[128];
  int tid = threadIdx.x;
  unsigned v = (tid < M) ? bsums[tid] : 0u;
  sm[tid] = v;
  __syncthreads();
  for (int ofs = 1; ofs < 128; ofs <<= 1) {
    unsigned add = (tid >= ofs) ? sm[tid - ofs] : 0u;
    __syncthreads();
    sm[tid] += add;
    __syncthreads();
  }
  if (tid < M) bsums[tid] = sm[tid] - v;
  if (tid == 127) offs[N] = sm[127];
}

__global__ __launch_bounds__(256) void scan_k3(
    unsigned* __restrict__ offs, const unsigned* __restrict__ bsums, int N) {
  int i = blockIdx.x * 256 + threadIdx.x;
  if (i < N) offs[i] = offs[i] + bsums[i >> 10];
}

__global__ __launch_bounds__(128) void bin_init_kernel(
    const unsigned* __restrict__ offs, unsigned* __restrict__ bincur, int nbins) {
  int b = threadIdx.x;
  if (b < nbins) bincur[b] = offs[b << 10];
}

// pass 1: block-aggregated scatter into dst-bins.
#define SCHUNK 2048
__global__ __launch_bounds__(256) void bin_scatter_kernel(
    const int* __restrict__ src, const int* __restrict__ dst,
    const int* __restrict__ rel, const float* __restrict__ norm,
    unsigned* __restrict__ bincur, uint2* __restrict__ binbuf, int E) {
  __shared__ unsigned cnt[128];
  __shared__ unsigned base[128];
  int tid = threadIdx.x;
  int start = blockIdx.x * SCHUNK;
  if (tid < 128) cnt[tid] = 0u;
  __syncthreads();
  unsigned mybin[8];
  uint2 myrec[8];
#pragma unroll
  for (int i = 0; i < 8; ++i) {
    int e = start + i * 256 + tid;
    if (e < E) {
      int d = dst[e];
      mybin[i] = (unsigned)d >> 10;
      myrec[i].x = (unsigned)src[e] | ((unsigned)rel[e] << 17) |
                   ((unsigned)(d & 1023) << 19);
      myrec[i].y = __builtin_bit_cast(unsigned, norm[e]);
      atomicAdd(&cnt[mybin[i]], 1u);
    } else {
      mybin[i] = 0xFFFFFFFFu;
    }
  }
  __syncthreads();
  if (tid < 128) {
    unsigned c = cnt[tid];
    base[tid] = c ? atomicAdd(&bincur[tid], c) : 0u;
    cnt[tid] = 0u;
  }
  __syncthreads();
#pragma unroll
  for (int i = 0; i < 8; ++i) {
    if (mybin[i] != 0xFFFFFFFFu) {
      unsigned r = atomicAdd(&cnt[mybin[i]], 1u);
      binbuf[base[mybin[i]] + r] = myrec[i];
    }
  }
}

// pass 2: per-bin counting sort into final CSR positions (writes L2-resident)
__global__ __launch_bounds__(1024) void bin_sort_kernel(
    const uint2* __restrict__ binbuf, const unsigned* __restrict__ offs,
    uint2* __restrict__ epack, int N) {
  __shared__ unsigned cnt[1024];
  __shared__ unsigned offl[1024];
  int bin = blockIdx.x;
  int base = bin << 10;
  int tid = threadIdx.x;
  int hi = base + 1024;
  if (hi > N) hi = N;
  if (base + tid < N) offl[tid] = offs[base + tid];
  cnt[tid] = 0u;
  __syncthreads();
  unsigned start = offs[base];
  unsigned end = offs[hi];
  for (unsigned j = start + tid; j < end; j += 1024) {
    uint2 rec = binbuf[j];
    unsigned dlo = rec.x >> 19;
    unsigned r = atomicAdd(&cnt[dlo], 1u);
    epack[offl[dlo] + r] = rec;
  }
}

// ---------------- transform (MFMA): t[r][n][e] = sum_d x[n][d] W[r][d][e] ----------------

__global__ __launch_bounds__(256) void transform_kernel(
    const unsigned short* __restrict__ xhi, const unsigned short* __restrict__ xlo,
    const unsigned short* __restrict__ wfrag, float* __restrict__ t, int N, int NT) {
  int lane = threadIdx.x & 63;
  int w = threadIdx.x >> 6;
  bf16x8 bh[3][2], bl[3][2];
  const short8* fh = (const short8*)wfrag;
  const short8* fl = (const short8*)(wfrag + 12288);
#pragma unroll
  for (int ct = 0; ct < 3; ++ct)
#pragma unroll
    for (int ks = 0; ks < 2; ++ks) {
      int tci = w * 3 + ct;
      bh[ct][ks] = __builtin_bit_cast(bf16x8, fh[(tci * 2 + ks) * 64 + lane]);
      bl[ct][ks] = __builtin_bit_cast(bf16x8, fl[(tci * 2 + ks) * 64 + lane]);
    }
  int r15 = lane & 15, kq = lane >> 4;
  for (int nt = blockIdx.x; nt < NT; nt += gridDim.x) {
    int n0 = nt * 16;
    int row = n0 + r15;
    if (row >= N) row = N - 1;
    const short8* ah = (const short8*)(xhi + (((size_t)row) << 6) + (kq << 3));
    const short8* al = (const short8*)(xlo + (((size_t)row) << 6) + (kq << 3));
    bf16x8 axh[2], axl[2];
    axh[0] = __builtin_bit_cast(bf16x8, ah[0]);
    axh[1] = __builtin_bit_cast(bf16x8, ah[4]);
    axl[0] = __builtin_bit_cast(bf16x8, al[0]);
    axl[1] = __builtin_bit_cast(bf16x8, al[4]);
#pragma unroll
    for (int ct = 0; ct < 3; ++ct) {
      f32x4 acc = {0.f, 0.f, 0.f, 0.f};
#pragma unroll
      for (int ks = 0; ks < 2; ++ks) {
        acc = MFMA16(axh[ks], bh[ct][ks], acc);
        acc = MFMA16(axh[ks], bl[ct][ks], acc);
        acc = MFMA16(axl[ks], bh[ct][ks], acc);
      }
      int c = (w * 3 + ct) * 16 + r15;
      int rrel = c >> 6, e = c & 63;
      float* tb = t + (((size_t)rrel * N) << 6) + e;
#pragma unroll
      for (int reg = 0; reg < 4; ++reg) {
        int n = n0 + (kq << 2) + reg;
        if (n < N) tb[((size_t)n) << 6] = acc[reg];
      }
    }
  }
}

// ---------------- gather: 4 edges in flight per wave (16-lane groups) ----------------

__global__ __launch_bounds__(256) void gather_kernel(
    const float* __restrict__ t, const unsigned* __restrict__ offs,
    const uint2* __restrict__ epack,
    unsigned short* __restrict__ swhhi, unsigned short* __restrict__ swhlo, int N) {
  int tid = threadIdx.x;
  int lane = tid & 63;
  int n = __builtin_amdgcn_readfirstlane(blockIdx.x * 4 + (tid >> 6));
  if (n >= N) return;
  unsigned a = offs[n], b = offs[n + 1];
  int g = lane >> 4;          // edge group 0..3
  int cl = (lane & 15) << 2;  // channel base
  float acc0 = 0.f, acc1 = 0.f, acc2 = 0.f, acc3 = 0.f;
  for (unsigned j = a + g; j < b; j += 4) {
    uint2 e = epack[j];
    const float* row =
        t + (((size_t)((e.x >> 17) & 3) * N + (e.x & 0x1FFFFu)) << 6) + cl;
    float4 v = *(const float4*)row;
    float nv = __builtin_bit_cast(float, e.y);
    acc0 = fmaf(v.x, nv, acc0);
    acc1 = fmaf(v.y, nv, acc1);
    acc2 = fmaf(v.z, nv, acc2);
    acc3 = fmaf(v.w, nv, acc3);
  }
  acc0 += __shfl_xor(acc0, 16);
  acc1 += __shfl_xor(acc1, 16);
  acc2 += __shfl_xor(acc2, 16);
  acc3 += __shfl_xor(acc3, 16);
  acc0 += __shfl_xor(acc0, 32);
  acc1 += __shfl_xor(acc1, 32);
  acc2 += __shfl_xor(acc2, 32);
  acc3 += __shfl_xor(acc3, 32);
  if (g == 0) {
    ushort4 h, l;
    split2(acc0, &h.x, &l.x);
    split2(acc1, &h.y, &l.y);
    split2(acc2, &h.z, &l.z);
    split2(acc3, &h.w, &l.w);
    *(ushort4*)(swhhi + (((size_t)n) << 6) + cl) = h;
    *(ushort4*)(swhlo + (((size_t)n) << 6) + cl) = l;
  }
}

// ---------------- fused GRU: all gates per wave, no LDS, no barriers ----------------
// Wave w owns 16-col slice c = w*16 + (lane&15) for gates r,z,n (tci = g*4+w).
// MFMA D layout: col = lane&15, row = 4*(lane>>4)+reg -> all 3 gates for a
// given (node, col) land in the same lane/reg -> gate math is register-only.

template <int USE_H, int WRITE_SPLIT>
__global__ __launch_bounds__(256) void gru_kernel(
    const unsigned short* __restrict__ xhi, const unsigned short* __restrict__ xlo,
    const unsigned short* __restrict__ hhi, const unsigned short* __restrict__ hlo,
    const float* __restrict__ hprev,
    const unsigned short* __restrict__ wfi, const unsigned short* __restrict__ wfh,
    const float* __restrict__ b_ih, const float* __restrict__ b_hh,
    float* __restrict__ hout, unsigned short* __restrict__ houthi,
    unsigned short* __restrict__ houtlo, int N) {
  int lane = threadIdx.x & 63;
  int w = threadIdx.x >> 6;
  int r15 = lane & 15, kq = lane >> 4;
  int c = (w << 4) + r15;

  const short8* fih = (const short8*)wfi;
  const short8* fil = (const short8*)(wfi + 12288);
  const short8* fhh = (const short8*)wfh;
  const short8* fhl = (const short8*)(wfh + 12288);
  bf16x8 bih[3][2], bil[3][2], bhh[3][2], bhl[3][2];
#pragma unroll
  for (int g = 0; g < 3; ++g)
#pragma unroll
    for (int ks = 0; ks < 2; ++ks) {
      int tci = (g << 2) + w;
      bih[g][ks] = __builtin_bit_cast(bf16x8, fih[(tci * 2 + ks) * 64 + lane]);
      bil[g][ks] = __builtin_bit_cast(bf16x8, fil[(tci * 2 + ks) * 64 + lane]);
      if (USE_H) {
        bhh[g][ks] = __builtin_bit_cast(bf16x8, fhh[(tci * 2 + ks) * 64 + lane]);
        bhl[g][ks] = __builtin_bit_cast(bf16x8, fhl[(tci * 2 + ks) * 64 + lane]);
      }
    }
  float bi[3], bh[3];
#pragma unroll
  for (int g = 0; g < 3; ++g) {
    bi[g] = b_ih[(g << 6) + c];
    bh[g] = b_hh[(g << 6) + c];
  }

  int n0 = blockIdx.x << 4;
  int row = n0 + r15;  // N % 16 == 0 for this problem; guarded below anyway
  if (row >= N) row = N - 1;

  bf16x8 axh[2], axl[2], ahh2[2], ahl2[2];
  {
    const short8* ax0 = (const short8*)(xhi + (((size_t)row) << 6) + (kq << 3));
    const short8* ax1 = (const short8*)(xlo + (((size_t)row) << 6) + (kq << 3));
    axh[0] = __builtin_bit_cast(bf16x8, ax0[0]);
    axh[1] = __builtin_bit_cast(bf16x8, ax0[4]);
    axl[0] = __builtin_bit_cast(bf16x8, ax1[0]);
    axl[1] = __builtin_bit_cast(bf16x8, ax1[4]);
    if (USE_H) {
      const short8* ah0 = (const short8*)(hhi + (((size_t)row) << 6) + (kq << 3));
      const short8* ah1 = (const short8*)(hlo + (((size_t)row) << 6) + (kq << 3));
      ahh2[0] = __builtin_bit_cast(bf16x8, ah0[0]);
      ahh2[1] = __builtin_bit_cast(bf16x8, ah0[4]);
      ahl2[0] = __builtin_bit_cast(bf16x8, ah1[0]);
      ahl2[1] = __builtin_bit_cast(bf16x8, ah1[4]);
    }
  }

  f32x4 accx[3], acch[3];
#pragma unroll
  for (int g = 0; g < 3; ++g) {
    accx[g] = (f32x4){0.f, 0.f, 0.f, 0.f};
    acch[g] = (f32x4){0.f, 0.f, 0.f, 0.f};
#pragma unroll
    for (int ks = 0; ks < 2; ++ks) {
      accx[g] = MFMA16(axh[ks], bih[g][ks], accx[g]);
      accx[g] = MFMA16(axh[ks], bil[g][ks], accx[g]);
      accx[g] = MFMA16(axl[ks], bih[g][ks], accx[g]);
      if (USE_H) {
        acch[g] = MFMA16(ahh2[ks], bhh[g][ks], acch[g]);
        acch[g] = MFMA16(ahh2[ks], bhl[g][ks], acch[g]);
        acch[g] = MFMA16(ahl2[ks], bhh[g][ks], acch[g]);
      }
    }
  }

#pragma unroll
  for (int reg = 0; reg < 4; ++reg) {
    int n = n0 + (kq << 2) + reg;
    if (n >= N) break;
    float hp = 0.f;
    if (USE_H) hp = hprev[(((size_t)n) << 6) + c];
    float gir = accx[0][reg] + bi[0];
    float giz = accx[1][reg] + bi[1];
    float gin = accx[2][reg] + bi[2];
    float ghr = (USE_H ? acch[0][reg] : 0.f) + bh[0];
    float ghz = (USE_H ? acch[1][reg] : 0.f) + bh[1];
    float ghn = (USE_H ? acch[2][reg] : 0.f) + bh[2];
    float r = 1.f / (1.f + __expf(-(gir + ghr)));
    float z = 1.f / (1.f + __expf(-(giz + ghz)));
    float nn = tanhf(gin + r * ghn);
    float o = (1.f - z) * nn + z * hp;
    hout[(((size_t)n) << 6) + c] = o;
    if (WRITE_SPLIT) {
      unsigned short oh, ol;
      split2(o, &oh, &ol);
      houthi[(((size_t)n) << 6) + c] = oh;
      houtlo[(((size_t)n) << 6) + c] = ol;
    }
  }
}

// ---------------- batchnorm ----------------

__global__ __launch_bounds__(256) void bn_stats_kernel(
    const float* __restrict__ h, float* __restrict__ stats, int N) {
  int tid = threadIdx.x;
  int c = tid & 63;
  float s = 0.f, ss = 0.f;
  for (int n = blockIdx.x * 4 + (tid >> 6); n < N; n += gridDim.x * 4) {
    float v = h[(size_t)n * 64 + c];
    s += v;
    ss += v * v;
  }
  __shared__ float sm[2][256];
  sm[0][tid] = s;
  sm[1][tid] = ss;
  __syncthreads();
  if (tid < 64) {
    s = sm[0][tid] + sm[0][tid + 64] + sm[0][tid + 128] + sm[0][tid + 192];
    ss = sm[1][tid] + sm[1][tid + 64] + sm[1][tid + 128] + sm[1][tid + 192];
    atomicAdd(&stats[tid], s);
    atomicAdd(&stats[64 + tid], ss);
  }
}

__global__ __launch_bounds__(256) void bn_apply_kernel(
    float* out, const float* __restrict__ stats,
    const float* __restrict__ gamma, const float* __restrict__ beta,
    int N, int total) {
  int idx = blockIdx.x * 256 + threadIdx.x;
  if (idx >= total) return;
  int c = idx & 63;
  float invN = 1.f / (float)N;
  float mean = stats[c] * invN;
  float var = stats[64 + c] * invN - mean * mean;
  float sc = rsqrtf(var + 1e-5f) * gamma[c];
  float sh = beta[c] - mean * sc;
  out[idx] = out[idx] * sc + sh;
}

// ---------------- launch ----------------

extern "C" void kernel_launch(void* const* d_in, const int* in_sizes, int n_in,
                              void* d_out, int out_size, void* d_ws, size_t ws_size,
                              hipStream_t stream) {
  const float* h     = (const float*)d_in[0];
  const float* norm  = (const float*)d_in[1];
  const float* W     = (const float*)d_in[2];
  const float* w_ih  = (const float*)d_in[3];
  const float* w_hh  = (const float*)d_in[4];
  const float* b_ih  = (const float*)d_in[5];
  const float* b_hh  = (const float*)d_in[6];
  const float* gamma = (const float*)d_in[7];
  const float* beta  = (const float*)d_in[8];
  const int* src     = (const int*)d_in[9];
  const int* dst     = (const int*)d_in[10];
  const int* rel     = (const int*)d_in[11];
  float* out = (float*)d_out;

  const int N = in_sizes[0] / 64;
  const int E = in_sizes[1];
  const int NT = (N + 15) / 16;
  const int NBINS = (N + 1023) / 1024;

  char* wsp = (char*)d_ws;
  float* t = (float*)wsp;              wsp += (size_t)3 * N * 64 * 4;
  unsigned short* xhi = (unsigned short*)wsp; wsp += (size_t)N * 64 * 2;
  unsigned short* xlo = (unsigned short*)wsp; wsp += (size_t)N * 64 * 2;
  unsigned short* swhhi = (unsigned short*)wsp; wsp += (size_t)N * 64 * 2;
  unsigned short* swhlo = (unsigned short*)wsp; wsp += (size_t)N * 64 * 2;
  unsigned short* frags = (unsigned short*)wsp; wsp += 6 * 12288 * 2;
  unsigned* offs = (unsigned*)wsp;   wsp += ((size_t)N + 4) * 4;
  unsigned* cursor = (unsigned*)wsp; wsp += (size_t)N * 4;
  uint2* epack = (uint2*)wsp;        wsp += (size_t)E * 8;
  unsigned* bsums = (unsigned*)wsp;  wsp += 128 * 4;
  float* stats = (float*)wsp;        wsp += 128 * 4;

  uint2* binbuf = (uint2*)t;  // aliases t: dead until transform
  unsigned* bincur = cursor;  // reuse per-dst counter buffer (dead after scan)

  const unsigned short* frag_t = frags;
  const unsigned short* frag_i = frags + 2 * 12288;
  const unsigned short* frag_h = frags + 4 * 12288;

  const int M = (N + 1023) / 1024;

  hipMemsetAsync(cursor, 0, (size_t)N * 4, stream);
  hipMemsetAsync(stats, 0, 128 * 4, stream);

  wprep_kernel<<<18, 256, 0, stream>>>(W, w_ih, w_hh, frags);
  conv_split_kernel<<<(N * 16 + 255) / 256, 256, 0, stream>>>(h, xhi, xlo, N * 16);

  // CSR over dst (graph is layer-invariant): count -> scan -> binned sort
  count_kernel<<<(E / 4 + 255) / 256, 256, 0, stream>>>(dst, cursor, E);
  scan_k1<<<M, 1024, 0, stream>>>(cursor, offs, bsums, N);
  scan_k2<<<1, 128, 0, stream>>>(bsums, offs, M, N);
  scan_k3<<<(N + 255) / 256, 256, 0, stream>>>(offs, bsums, N);
  bin_init_kernel<<<1, 128, 0, stream>>>(offs, bincur, NBINS);
  bin_scatter_kernel<<<(E + SCHUNK - 1) / SCHUNK, 256, 0, stream>>>(
      src, dst, rel, norm, bincur, binbuf, E);
  bin_sort_kernel<<<NBINS, 1024, 0, stream>>>(binbuf, offs, epack, N);

  // layer 0 (hstate = 0): gru writes h1 fp32 -> out, h1 split -> xhi/xlo
  transform_kernel<<<1024, 256, 0, stream>>>(xhi, xlo, frag_t, t, N, NT);
  gather_kernel<<<(N + 3) / 4, 256, 0, stream>>>(t, offs, epack, swhhi, swhlo, N);
  gru_kernel<0, 1><<<NT, 256, 0, stream>>>(swhhi, swhlo, nullptr, nullptr, nullptr,
                                           frag_i, frag_h, b_ih, b_hh,
                                           out, xhi, xlo, N);

  // layer 1: transform reads h1 split; gru h-path reads h1 split, hprev = out
  transform_kernel<<<1024, 256, 0, stream>>>(xhi, xlo, frag_t, t, N, NT);
  gather_kernel<<<(N + 3) / 4, 256, 0, stream>>>(t, offs, epack, swhhi, swhlo, N);
  gru_kernel<1, 0><<<NT, 256, 0, stream>>>(swhhi, swhlo, xhi, xlo, out,
                                           frag_i, frag_h, b_ih, b_hh,
                                           out, nullptr, nullptr, N);

  bn_stats_kernel<<<256, 256, 0, stream>>>(out, stats, N);
  int total = N * 64;
  bn_apply_kernel<<<(total + 255) / 256, 256, 0, stream>>>(out, stats, gamma,
                                                           beta, N, total);
}

// Round 9
// 352.121 us; speedup vs baseline: 1.0397x; 1.0397x over previous
//
#include <hip/hip_runtime.h>

typedef __bf16 bf16x8 __attribute__((ext_vector_type(8)));
typedef float f32x4 __attribute__((ext_vector_type(4)));
typedef short short8 __attribute__((ext_vector_type(8)));

#define MFMA16(a, b, c) __builtin_amdgcn_mfma_f32_16x16x32_bf16(a, b, c, 0, 0, 0)

__device__ inline unsigned short bf16_rne(float x) {
  unsigned u = __builtin_bit_cast(unsigned, x);
  return (unsigned short)((u + 0x7FFFu + ((u >> 16) & 1u)) >> 16);
}
__device__ inline float bf16_tof(unsigned short s) {
  unsigned u = ((unsigned)s) << 16;
  return __builtin_bit_cast(float, u);
}
__device__ inline void split2(float x, unsigned short* hi, unsigned short* lo) {
  unsigned short h = bf16_rne(x);
  *hi = h;
  *lo = bf16_rne(x - bf16_tof(h));
}
__device__ inline float fast_rcp(float x) { return __builtin_amdgcn_rcpf(x); }

// ---------------- fp32 -> (hi, lo) bf16 split ----------------

__global__ __launch_bounds__(256) void conv_split_kernel(
    const float* __restrict__ x, unsigned short* __restrict__ xhi,
    unsigned short* __restrict__ xlo, int total4) {
  int i = blockIdx.x * 256 + threadIdx.x;
  if (i < total4) {
    float4 v = ((const float4*)x)[i];
    ushort4 h, l;
    split2(v.x, &h.x, &l.x);
    split2(v.y, &h.y, &l.y);
    split2(v.z, &h.z, &l.z);
    split2(v.w, &h.w, &l.w);
    ((ushort4*)xhi)[i] = h;
    ((ushort4*)xlo)[i] = l;
  }
}

// ---------------- weight frag prep ----------------

__global__ __launch_bounds__(256) void wprep_kernel(
    const float* __restrict__ W, const float* __restrict__ w_ih,
    const float* __restrict__ w_hh, unsigned short* __restrict__ frags) {
  int idx = blockIdx.x * 256 + threadIdx.x;
  if (idx >= 3 * 12 * 2 * 64) return;
  int lane = idx & 63;
  int ks = (idx >> 6) & 1;
  int tci = (idx >> 7) % 12;
  int set = idx / (12 * 2 * 64);
  int c = tci * 16 + (lane & 15);
  unsigned short* hi = frags + (size_t)set * 2 * 12288;
  unsigned short* lo = hi + 12288;
  size_t dbase = ((size_t)(tci * 2 + ks) * 64 + lane) * 8;
#pragma unroll
  for (int j = 0; j < 8; ++j) {
    int k = ks * 32 + ((lane >> 4) << 3) + j;
    float v;
    if (set == 0) v = W[((c >> 6) << 12) + (k << 6) + (c & 63)];
    else if (set == 1) v = w_ih[(c << 6) + k];
    else v = w_hh[(c << 6) + k];
    unsigned short h, l;
    split2(v, &h, &l);
    hi[dbase + j] = h;
    lo[dbase + j] = l;
  }
}

// ---------------- CSR build ----------------

__global__ __launch_bounds__(256) void count_kernel(
    const int* __restrict__ dst, unsigned* __restrict__ counts, int E) {
  int base = (blockIdx.x * 256 + threadIdx.x) * 4;
  if (base + 4 <= E) {
    int4 d = *(const int4*)(dst + base);
    atomicAdd(&counts[d.x], 1u);
    atomicAdd(&counts[d.y], 1u);
    atomicAdd(&counts[d.z], 1u);
    atomicAdd(&counts[d.w], 1u);
  } else {
    for (int k = base; k < E; ++k) atomicAdd(&counts[dst[k]], 1u);
  }
}

__global__ __launch_bounds__(1024) void scan_k1(
    const unsigned* __restrict__ counts, unsigned* __restrict__ offs,
    unsigned* __restrict__ bsums, int N) {
  __shared__ unsigned sm[1024];
  int tid = threadIdx.x;
  int i = blockIdx.x * 1024 + tid;
  unsigned v = (i < N) ? counts[i] : 0u;
  sm[tid] = v;
  __syncthreads();
  for (int ofs = 1; ofs < 1024; ofs <<= 1) {
    unsigned add = (tid >= ofs) ? sm[tid - ofs] : 0u;
    __syncthreads();
    sm[tid] += add;
    __syncthreads();
  }
  if (i < N) offs[i] = sm[tid] - v;
  if (tid == 0) bsums[blockIdx.x] = sm[1023];
}

__global__ __launch_bounds__(128) void scan_k2(
    unsigned* __restrict__ bsums, unsigned* __restrict__ offs, int M, int N) {
  __shared__ unsigned sm[128];
  int tid = threadIdx.x;
  unsigned v = (tid < M) ? bsums[tid] : 0u;
  sm[tid] = v;
  __syncthreads();
  for (int ofs = 1; ofs < 128; ofs <<= 1) {
    unsigned add = (tid >= ofs) ? sm[tid - ofs] : 0u;
    __syncthreads();
    sm[tid] += add;
    __syncthreads();
  }
  if (tid < M) bsums[tid] = sm[tid] - v;
  if (tid == 127) offs[N] = sm[127];
}

__global__ __launch_bounds__(256) void scan_k3(
    unsigned* __restrict__ offs, const unsigned* __restrict__ bsums, int N) {
  int i = blockIdx.x * 256 + threadIdx.x;
  if (i < N) offs[i] = offs[i] + bsums[i >> 10];
}

__global__ __launch_bounds__(128) void bin_init_kernel(
    const unsigned* __restrict__ offs, unsigned* __restrict__ bincur, int nbins) {
  int b = threadIdx.x;
  if (b < nbins) bincur[b] = offs[b << 10];
}

// pass 1: block-aggregated scatter into dst-bins.
#define SCHUNK 2048
__global__ __launch_bounds__(256) void bin_scatter_kernel(
    const int* __restrict__ src, const int* __restrict__ dst,
    const int* __restrict__ rel, const float* __restrict__ norm,
    unsigned* __restrict__ bincur, uint2* __restrict__ binbuf, int E) {
  __shared__ unsigned cnt[128];
  __shared__ unsigned base[128];
  int tid = threadIdx.x;
  int start = blockIdx.x * SCHUNK;
  if (tid < 128) cnt[tid] = 0u;
  __syncthreads();
  unsigned mybin[8];
  uint2 myrec[8];
#pragma unroll
  for (int i = 0; i < 8; ++i) {
    int e = start + i * 256 + tid;
    if (e < E) {
      int d = dst[e];
      mybin[i] = (unsigned)d >> 10;
      myrec[i].x = (unsigned)src[e] | ((unsigned)rel[e] << 17) |
                   ((unsigned)(d & 1023) << 19);
      myrec[i].y = __builtin_bit_cast(unsigned, norm[e]);
      atomicAdd(&cnt[mybin[i]], 1u);
    } else {
      mybin[i] = 0xFFFFFFFFu;
    }
  }
  __syncthreads();
  if (tid < 128) {
    unsigned c = cnt[tid];
    base[tid] = c ? atomicAdd(&bincur[tid], c) : 0u;
    cnt[tid] = 0u;
  }
  __syncthreads();
#pragma unroll
  for (int i = 0; i < 8; ++i) {
    if (mybin[i] != 0xFFFFFFFFu) {
      unsigned r = atomicAdd(&cnt[mybin[i]], 1u);
      binbuf[base[mybin[i]] + r] = myrec[i];
    }
  }
}

// pass 2: per-bin counting sort into final CSR positions (writes L2-resident)
__global__ __launch_bounds__(1024) void bin_sort_kernel(
    const uint2* __restrict__ binbuf, const unsigned* __restrict__ offs,
    uint2* __restrict__ epack, int N) {
  __shared__ unsigned cnt[1024];
  __shared__ unsigned offl[1024];
  int bin = blockIdx.x;
  int base = bin << 10;
  int tid = threadIdx.x;
  int hi = base + 1024;
  if (hi > N) hi = N;
  if (base + tid < N) offl[tid] = offs[base + tid];
  cnt[tid] = 0u;
  __syncthreads();
  unsigned start = offs[base];
  unsigned end = offs[hi];
  for (unsigned j = start + tid; j < end; j += 1024) {
    uint2 rec = binbuf[j];
    unsigned dlo = rec.x >> 19;
    unsigned r = atomicAdd(&cnt[dlo], 1u);
    epack[offl[dlo] + r] = rec;
  }
}

// ---------------- transform (MFMA): t[r][n][e] = sum_d x[n][d] W[r][d][e] ----------------

__global__ __launch_bounds__(256) void transform_kernel(
    const unsigned short* __restrict__ xhi, const unsigned short* __restrict__ xlo,
    const unsigned short* __restrict__ wfrag, float* __restrict__ t, int N, int NT) {
  int lane = threadIdx.x & 63;
  int w = threadIdx.x >> 6;
  bf16x8 bh[3][2], bl[3][2];
  const short8* fh = (const short8*)wfrag;
  const short8* fl = (const short8*)(wfrag + 12288);
#pragma unroll
  for (int ct = 0; ct < 3; ++ct)
#pragma unroll
    for (int ks = 0; ks < 2; ++ks) {
      int tci = w * 3 + ct;
      bh[ct][ks] = __builtin_bit_cast(bf16x8, fh[(tci * 2 + ks) * 64 + lane]);
      bl[ct][ks] = __builtin_bit_cast(bf16x8, fl[(tci * 2 + ks) * 64 + lane]);
    }
  int r15 = lane & 15, kq = lane >> 4;
  for (int nt = blockIdx.x; nt < NT; nt += gridDim.x) {
    int n0 = nt * 16;
    int row = n0 + r15;
    if (row >= N) row = N - 1;
    const short8* ah = (const short8*)(xhi + (((size_t)row) << 6) + (kq << 3));
    const short8* al = (const short8*)(xlo + (((size_t)row) << 6) + (kq << 3));
    bf16x8 axh[2], axl[2];
    axh[0] = __builtin_bit_cast(bf16x8, ah[0]);
    axh[1] = __builtin_bit_cast(bf16x8, ah[4]);
    axl[0] = __builtin_bit_cast(bf16x8, al[0]);
    axl[1] = __builtin_bit_cast(bf16x8, al[4]);
#pragma unroll
    for (int ct = 0; ct < 3; ++ct) {
      f32x4 acc = {0.f, 0.f, 0.f, 0.f};
#pragma unroll
      for (int ks = 0; ks < 2; ++ks) {
        acc = MFMA16(axh[ks], bh[ct][ks], acc);
        acc = MFMA16(axh[ks], bl[ct][ks], acc);
        acc = MFMA16(axl[ks], bh[ct][ks], acc);
      }
      int c = (w * 3 + ct) * 16 + r15;
      int rrel = c >> 6, e = c & 63;
      float* tb = t + (((size_t)rrel * N) << 6) + e;
#pragma unroll
      for (int reg = 0; reg < 4; ++reg) {
        int n = n0 + (kq << 2) + reg;
        if (n < N) tb[((size_t)n) << 6] = acc[reg];
      }
    }
  }
}

// ---------------- gather: 4 edges in flight per wave (16-lane groups) ----------------

__global__ __launch_bounds__(256) void gather_kernel(
    const float* __restrict__ t, const unsigned* __restrict__ offs,
    const uint2* __restrict__ epack,
    unsigned short* __restrict__ swhhi, unsigned short* __restrict__ swhlo, int N) {
  int tid = threadIdx.x;
  int lane = tid & 63;
  int n = __builtin_amdgcn_readfirstlane(blockIdx.x * 4 + (tid >> 6));
  if (n >= N) return;
  unsigned a = offs[n], b = offs[n + 1];
  int g = lane >> 4;          // edge group 0..3
  int cl = (lane & 15) << 2;  // channel base
  float acc0 = 0.f, acc1 = 0.f, acc2 = 0.f, acc3 = 0.f;
  for (unsigned j = a + g; j < b; j += 4) {
    uint2 e = epack[j];
    const float* row =
        t + (((size_t)((e.x >> 17) & 3) * N + (e.x & 0x1FFFFu)) << 6) + cl;
    float4 v = *(const float4*)row;
    float nv = __builtin_bit_cast(float, e.y);
    acc0 = fmaf(v.x, nv, acc0);
    acc1 = fmaf(v.y, nv, acc1);
    acc2 = fmaf(v.z, nv, acc2);
    acc3 = fmaf(v.w, nv, acc3);
  }
  acc0 += __shfl_xor(acc0, 16);
  acc1 += __shfl_xor(acc1, 16);
  acc2 += __shfl_xor(acc2, 16);
  acc3 += __shfl_xor(acc3, 16);
  acc0 += __shfl_xor(acc0, 32);
  acc1 += __shfl_xor(acc1, 32);
  acc2 += __shfl_xor(acc2, 32);
  acc3 += __shfl_xor(acc3, 32);
  if (g == 0) {
    ushort4 h, l;
    split2(acc0, &h.x, &l.x);
    split2(acc1, &h.y, &l.y);
    split2(acc2, &h.z, &l.z);
    split2(acc3, &h.w, &l.w);
    *(ushort4*)(swhhi + (((size_t)n) << 6) + cl) = h;
    *(ushort4*)(swhlo + (((size_t)n) << 6) + cl) = l;
  }
}

// ---------------- fused GRU: register gates, grid-stride, weights resident ----------------
// Wave w owns 16-col slice c = w*16 + (lane&15) for gates r,z,n (tci = g*4+w).
// LAYER=0: hstate=0, writes split h1 only. LAYER=1: h from split (hp = hi+lo
// reconstruction), writes fp32 out, accumulates BN stats.

template <int LAYER>
__global__ __launch_bounds__(256) void gru_kernel(
    const unsigned short* __restrict__ shi, const unsigned short* __restrict__ slo,
    const unsigned short* __restrict__ hhi, const unsigned short* __restrict__ hlo,
    const unsigned short* __restrict__ wfi, const unsigned short* __restrict__ wfh,
    const float* __restrict__ b_ih, const float* __restrict__ b_hh,
    float* __restrict__ outf, unsigned short* __restrict__ houthi,
    unsigned short* __restrict__ houtlo, float* __restrict__ stats,
    int N, int NT) {
  int lane = threadIdx.x & 63;
  int w = threadIdx.x >> 6;
  int r15 = lane & 15, kq = lane >> 4;
  int c = (w << 4) + r15;

  const short8* fih = (const short8*)wfi;
  const short8* fil = (const short8*)(wfi + 12288);
  const short8* fhh = (const short8*)wfh;
  const short8* fhl = (const short8*)(wfh + 12288);
  bf16x8 bih[3][2], bil[3][2], bhh[3][2], bhl[3][2];
#pragma unroll
  for (int g = 0; g < 3; ++g)
#pragma unroll
    for (int ks = 0; ks < 2; ++ks) {
      int tci = (g << 2) + w;
      bih[g][ks] = __builtin_bit_cast(bf16x8, fih[(tci * 2 + ks) * 64 + lane]);
      bil[g][ks] = __builtin_bit_cast(bf16x8, fil[(tci * 2 + ks) * 64 + lane]);
      if (LAYER) {
        bhh[g][ks] = __builtin_bit_cast(bf16x8, fhh[(tci * 2 + ks) * 64 + lane]);
        bhl[g][ks] = __builtin_bit_cast(bf16x8, fhl[(tci * 2 + ks) * 64 + lane]);
      }
    }
  float bi[3], bh[3];
#pragma unroll
  for (int g = 0; g < 3; ++g) {
    bi[g] = b_ih[(g << 6) + c];
    bh[g] = b_hh[(g << 6) + c];
  }

  float bn_s = 0.f, bn_ss = 0.f;

  for (int nt = blockIdx.x; nt < NT; nt += gridDim.x) {
    int n0 = nt << 4;
    int row = n0 + r15;
    if (row >= N) row = N - 1;

    bf16x8 axh[2], axl[2], ahh2[2], ahl2[2];
    {
      const short8* ax0 = (const short8*)(shi + (((size_t)row) << 6) + (kq << 3));
      const short8* ax1 = (const short8*)(slo + (((size_t)row) << 6) + (kq << 3));
      axh[0] = __builtin_bit_cast(bf16x8, ax0[0]);
      axh[1] = __builtin_bit_cast(bf16x8, ax0[4]);
      axl[0] = __builtin_bit_cast(bf16x8, ax1[0]);
      axl[1] = __builtin_bit_cast(bf16x8, ax1[4]);
      if (LAYER) {
        const short8* ah0 = (const short8*)(hhi + (((size_t)row) << 6) + (kq << 3));
        const short8* ah1 = (const short8*)(hlo + (((size_t)row) << 6) + (kq << 3));
        ahh2[0] = __builtin_bit_cast(bf16x8, ah0[0]);
        ahh2[1] = __builtin_bit_cast(bf16x8, ah0[4]);
        ahl2[0] = __builtin_bit_cast(bf16x8, ah1[0]);
        ahl2[1] = __builtin_bit_cast(bf16x8, ah1[4]);
      }
    }

    f32x4 accx[3], acch[3];
#pragma unroll
    for (int g = 0; g < 3; ++g) {
      accx[g] = (f32x4){0.f, 0.f, 0.f, 0.f};
      acch[g] = (f32x4){0.f, 0.f, 0.f, 0.f};
#pragma unroll
      for (int ks = 0; ks < 2; ++ks) {
        accx[g] = MFMA16(axh[ks], bih[g][ks], accx[g]);
        accx[g] = MFMA16(axh[ks], bil[g][ks], accx[g]);
        accx[g] = MFMA16(axl[ks], bih[g][ks], accx[g]);
        if (LAYER) {
          acch[g] = MFMA16(ahh2[ks], bhh[g][ks], acch[g]);
          acch[g] = MFMA16(ahh2[ks], bhl[g][ks], acch[g]);
          acch[g] = MFMA16(ahl2[ks], bhh[g][ks], acch[g]);
        }
      }
    }

#pragma unroll
    for (int reg = 0; reg < 4; ++reg) {
      int n = n0 + (kq << 2) + reg;
      if (n >= N) break;
      size_t idx = (((size_t)n) << 6) + c;
      float hp = 0.f;
      if (LAYER) hp = bf16_tof(hhi[idx]) + bf16_tof(hlo[idx]);
      float gir = accx[0][reg] + bi[0];
      float giz = accx[1][reg] + bi[1];
      float gin = accx[2][reg] + bi[2];
      float ghr = (LAYER ? acch[0][reg] : 0.f) + bh[0];
      float ghz = (LAYER ? acch[1][reg] : 0.f) + bh[1];
      float ghn = (LAYER ? acch[2][reg] : 0.f) + bh[2];
      float r = fast_rcp(1.f + __expf(-(gir + ghr)));
      float z = fast_rcp(1.f + __expf(-(giz + ghz)));
      float nn = 1.f - 2.f * fast_rcp(1.f + __expf(2.f * (gin + r * ghn)));
      float o = (1.f - z) * nn + z * hp;
      if (LAYER) {
        outf[idx] = o;
        bn_s += o;
        bn_ss += o * o;
      } else {
        unsigned short oh, ol;
        split2(o, &oh, &ol);
        houthi[idx] = oh;
        houtlo[idx] = ol;
      }
    }
  }

  if (LAYER) {
    bn_s += __shfl_xor(bn_s, 16);
    bn_s += __shfl_xor(bn_s, 32);
    bn_ss += __shfl_xor(bn_ss, 16);
    bn_ss += __shfl_xor(bn_ss, 32);
    if (kq == 0) {
      atomicAdd(&stats[c], bn_s);
      atomicAdd(&stats[64 + c], bn_ss);
    }
  }
}

// ---------------- batchnorm apply ----------------

__global__ __launch_bounds__(256) void bn_apply_kernel(
    float* out, const float* __restrict__ stats,
    const float* __restrict__ gamma, const float* __restrict__ beta,
    int N, int total) {
  int idx = blockIdx.x * 256 + threadIdx.x;
  if (idx >= total) return;
  int c = idx & 63;
  float invN = 1.f / (float)N;
  float mean = stats[c] * invN;
  float var = stats[64 + c] * invN - mean * mean;
  float sc = rsqrtf(var + 1e-5f) * gamma[c];
  float sh = beta[c] - mean * sc;
  out[idx] = out[idx] * sc + sh;
}

// ---------------- launch ----------------

extern "C" void kernel_launch(void* const* d_in, const int* in_sizes, int n_in,
                              void* d_out, int out_size, void* d_ws, size_t ws_size,
                              hipStream_t stream) {
  const float* h     = (const float*)d_in[0];
  const float* norm  = (const float*)d_in[1];
  const float* W     = (const float*)d_in[2];
  const float* w_ih  = (const float*)d_in[3];
  const float* w_hh  = (const float*)d_in[4];
  const float* b_ih  = (const float*)d_in[5];
  const float* b_hh  = (const float*)d_in[6];
  const float* gamma = (const float*)d_in[7];
  const float* beta  = (const float*)d_in[8];
  const int* src     = (const int*)d_in[9];
  const int* dst     = (const int*)d_in[10];
  const int* rel     = (const int*)d_in[11];
  float* out = (float*)d_out;

  const int N = in_sizes[0] / 64;
  const int E = in_sizes[1];
  const int NT = (N + 15) / 16;
  const int NBINS = (N + 1023) / 1024;

  char* wsp = (char*)d_ws;
  float* t = (float*)wsp;              wsp += (size_t)3 * N * 64 * 4;
  unsigned short* xhi = (unsigned short*)wsp; wsp += (size_t)N * 64 * 2;
  unsigned short* xlo = (unsigned short*)wsp; wsp += (size_t)N * 64 * 2;
  unsigned short* swhhi = (unsigned short*)wsp; wsp += (size_t)N * 64 * 2;
  unsigned short* swhlo = (unsigned short*)wsp; wsp += (size_t)N * 64 * 2;
  unsigned short* frags = (unsigned short*)wsp; wsp += 6 * 12288 * 2;
  unsigned* offs = (unsigned*)wsp;   wsp += ((size_t)N + 4) * 4;
  unsigned* cursor = (unsigned*)wsp; wsp += (size_t)N * 4;
  uint2* epack = (uint2*)wsp;        wsp += (size_t)E * 8;
  unsigned* bsums = (unsigned*)wsp;  wsp += 128 * 4;
  float* stats = (float*)wsp;        wsp += 128 * 4;

  uint2* binbuf = (uint2*)t;  // aliases t: dead until transform
  unsigned* bincur = cursor;  // reuse per-dst counter buffer (dead after scan)

  const unsigned short* frag_t = frags;
  const unsigned short* frag_i = frags + 2 * 12288;
  const unsigned short* frag_h = frags + 4 * 12288;

  const int M = (N + 1023) / 1024;

  hipMemsetAsync(cursor, 0, (size_t)N * 4, stream);
  hipMemsetAsync(stats, 0, 128 * 4, stream);

  wprep_kernel<<<18, 256, 0, stream>>>(W, w_ih, w_hh, frags);
  conv_split_kernel<<<(N * 16 + 255) / 256, 256, 0, stream>>>(h, xhi, xlo, N * 16);

  // CSR over dst (graph is layer-invariant): count -> scan -> binned sort
  count_kernel<<<(E / 4 + 255) / 256, 256, 0, stream>>>(dst, cursor, E);
  scan_k1<<<M, 1024, 0, stream>>>(cursor, offs, bsums, N);
  scan_k2<<<1, 128, 0, stream>>>(bsums, offs, M, N);
  scan_k3<<<(N + 255) / 256, 256, 0, stream>>>(offs, bsums, N);
  bin_init_kernel<<<1, 128, 0, stream>>>(offs, bincur, NBINS);
  bin_scatter_kernel<<<(E + SCHUNK - 1) / SCHUNK, 256, 0, stream>>>(
      src, dst, rel, norm, bincur, binbuf, E);
  bin_sort_kernel<<<NBINS, 1024, 0, stream>>>(binbuf, offs, epack, N);

  // layer 0 (hstate = 0): writes h1 split only -> xhi/xlo
  transform_kernel<<<1024, 256, 0, stream>>>(xhi, xlo, frag_t, t, N, NT);
  gather_kernel<<<(N + 3) / 4, 256, 0, stream>>>(t, offs, epack, swhhi, swhlo, N);
  gru_kernel<0><<<1024, 256, 0, stream>>>(swhhi, swhlo, nullptr, nullptr,
                                          frag_i, frag_h, b_ih, b_hh,
                                          nullptr, xhi, xlo, nullptr, N, NT);

  // layer 1: h from split (hp reconstructed); writes fp32 out + BN stats
  transform_kernel<<<1024, 256, 0, stream>>>(xhi, xlo, frag_t, t, N, NT);
  gather_kernel<<<(N + 3) / 4, 256, 0, stream>>>(t, offs, epack, swhhi, swhlo, N);
  gru_kernel<1><<<1024, 256, 0, stream>>>(swhhi, swhlo, xhi, xlo,
                                          frag_i, frag_h, b_ih, b_hh,
                                          out, nullptr, nullptr, stats, N, NT);

  int total = N * 64;
  bn_apply_kernel<<<(total + 255) / 256, 256, 0, stream>>>(out, stats, gamma,
                                                           beta, N, total);
}